// Round 2
// baseline (292.765 us; speedup 1.0000x reference)
//
#include <hip/hip_runtime.h>

#define HW 256
#define OW 254           // output rows/cols of the valid conv
#define TILE 32
#define SP_W 40          // sPred padded width (global cols j0-2 .. j0+37, clamped); mult of 4
#define SP_H 36          // sPred rows (global rows i0-2 .. i0+33, clamped)
#define SG_W 36          // sGS width: sx in [0,36); sx = gx+1, gx in [-1,34]; mult of 4
#define SG_H 34          // sGS rows: sy in [0,34); sy = gy+1, gy in [-1,32]
#define NOUT (256.0f * 254.0f * 254.0f)

__global__ __launch_bounds__(256) void pde_loss_main(
    const float* __restrict__ pred,
    const float* __restrict__ rhs,
    const float* __restrict__ Lk,
    const float* __restrict__ Dk,
    const float* __restrict__ RR,
    const float* __restrict__ ZZ,
    float* __restrict__ partial)
{
    __shared__ __align__(16) float sPred[SP_H * SP_W];
    __shared__ __align__(16) float sGS[SG_H * SG_W];
    __shared__ float sK[19];   // [0..8]=L, [9..17]=D, [18]=scale

    const int b  = blockIdx.z;
    const int i0 = blockIdx.y * TILE;
    const int j0 = blockIdx.x * TILE;
    const int tid = threadIdx.x;

    const float* predb = pred + (size_t)b * (HW * HW);
    const float* RRb   = RR   + (size_t)b * (HW * HW);
    const float* ZZb   = ZZ   + (size_t)b * (HW * HW);

    if (tid < 9) {
        sK[tid] = Lk[b * 9 + tid];
    } else if (tid < 18) {
        sK[tid] = Dk[b * 9 + (tid - 9)];
    } else if (tid == 18) {
        float hr = RRb[1 * HW + 2] - RRb[1 * HW + 1];
        float hz = ZZb[2 * HW + 1] - ZZb[1 * HW + 1];
        float hr2 = hr * hr, hz2 = hz * hz;
        sK[18] = (-2.0f * (hr2 + hz2)) / (hr2 * hz2);
    }

    // ---- Stage pred tile: rows i0-2..i0+33, cols j0-2..j0+37 (clamped). ----
    // Clamped cells are only consumed by GS points that get zeroed (guards).
    for (int idx = tid; idx < SP_H * SP_W; idx += 256) {
        int r = idx / SP_W, c = idx - r * SP_W;
        int gr = min(max(i0 - 2 + r, 0), HW - 1);
        int gc = min(max(j0 - 2 + c, 0), HW - 1);
        sPred[idx] = predb[gr * HW + gc];
    }
    __syncthreads();

    const float scale = sK[18];
    float kl[9], kd[9];
    #pragma unroll
    for (int q = 0; q < 9; q++) { kl[q] = sK[q]; kd[q] = sK[9 + q]; }

    // ---- Phase A: GS_ope on the 34-row x 36-col (padded) halo tile. ----
    // Each work unit = 4 consecutive sx positions, vectorized b128 LDS reads.
    for (int u = tid; u < SG_H * 9; u += 256) {
        int sy = u / 9;
        int g  = u - sy * 9;
        int c0 = g * 4;                 // sPred col base AND sGS col base
        int y  = i0 - 1 + sy;           // global conv-output row of this GS row

        float rows[3][8];
        #pragma unroll
        for (int q = 0; q < 3; q++) {
            const float4* p = (const float4*)&sPred[(sy + q) * SP_W + c0];
            float4 a = p[0], bb = p[1];
            rows[q][0] = a.x;  rows[q][1] = a.y;  rows[q][2] = a.z;  rows[q][3] = a.w;
            rows[q][4] = bb.x; rows[q][5] = bb.y; rows[q][6] = bb.z; rows[q][7] = bb.w;
        }

        bool rowok = (y >= 0) && (y < OW);
        float out4[4];
        #pragma unroll
        for (int e = 0; e < 4; e++) {
            int x = j0 + c0 + e - 1;    // global conv-output col (gx = sx-1)
            float gval = 0.0f;
            if (rowok && x >= 0 && x < OW) {
                float sL = 0.0f, sD = 0.0f;
                #pragma unroll
                for (int ky = 0; ky < 3; ky++) {
                    #pragma unroll
                    for (int kx = 0; kx < 3; kx++) {
                        float v = rows[ky][e + kx];
                        sL = fmaf(v, kl[ky * 3 + kx], sL);
                        sD = fmaf(v, kd[ky * 3 + kx], sD);
                    }
                }
                float rr = RRb[(y + 1) * HW + (x + 1)];
                // GS = (Lpsi + convD/RR) * scale ; v_rcp_f32: ~1e-7 rel err, fine
                gval = scale * fmaf(sD, __builtin_amdgcn_rcpf(rr), sL);
            }
            out4[e] = gval;
        }
        *(float4*)&sGS[sy * SG_W + c0] = make_float4(out4[0], out4[1], out4[2], out4[3]);
    }
    __syncthreads();

    // ---- Phase B: separable (1,2,1) blur + MSE, 4 consecutive outputs/thread ----
    const int oy = tid >> 3;            // 0..31
    const int c0 = (tid & 7) * 4;       // ox base, 16B aligned in sGS
    const int i  = i0 + oy;

    float h[3][4];
    #pragma unroll
    for (int q = 0; q < 3; q++) {
        const float4* p = (const float4*)&sGS[(oy + q) * SG_W + c0];
        float4 a = p[0], bb = p[1];
        float r[6] = {a.x, a.y, a.z, a.w, bb.x, bb.y};
        #pragma unroll
        for (int e = 0; e < 4; e++)
            h[q][e] = r[e] + 2.0f * r[e + 1] + r[e + 2];
    }

    float acc = 0.0f;
    #pragma unroll
    for (int e = 0; e < 4; e++) {
        int j = j0 + c0 + e;
        if (i < OW && j < OW) {
            float F = (h[0][e] + 2.0f * h[1][e] + h[2][e]) * (1.0f / 16.0f);
            float d = F - rhs[(size_t)b * (OW * OW) + i * OW + j];
            acc = fmaf(d, d, acc);
        }
    }

    // ---- wave (64) + block reduce ----
    #pragma unroll
    for (int off = 32; off > 0; off >>= 1)
        acc += __shfl_down(acc, off, 64);
    __shared__ float sw[4];
    int lane = tid & 63, w = tid >> 6;
    if (lane == 0) sw[w] = acc;
    __syncthreads();
    if (tid == 0) {
        partial[((size_t)blockIdx.z * gridDim.y + blockIdx.y) * gridDim.x + blockIdx.x]
            = sw[0] + sw[1] + sw[2] + sw[3];
    }
}

__global__ __launch_bounds__(256) void pde_loss_reduce(
    const float* __restrict__ partial, int n, float* __restrict__ out)
{
    float acc = 0.0f;
    for (int i = threadIdx.x; i < n; i += 256) acc += partial[i];
    #pragma unroll
    for (int off = 32; off > 0; off >>= 1)
        acc += __shfl_down(acc, off, 64);
    __shared__ float sw[4];
    if ((threadIdx.x & 63) == 0) sw[threadIdx.x >> 6] = acc;
    __syncthreads();
    if (threadIdx.x == 0)
        out[0] = (sw[0] + sw[1] + sw[2] + sw[3]) / NOUT;
}

extern "C" void kernel_launch(void* const* d_in, const int* in_sizes, int n_in,
                              void* d_out, int out_size, void* d_ws, size_t ws_size,
                              hipStream_t stream) {
    const float* pred = (const float*)d_in[0];
    const float* rhs  = (const float*)d_in[1];
    const float* Lk   = (const float*)d_in[2];
    const float* Dk   = (const float*)d_in[3];
    const float* RR   = (const float*)d_in[4];
    const float* ZZ   = (const float*)d_in[5];
    float* out = (float*)d_out;
    float* partial = (float*)d_ws;   // 8*8*256 = 16384 floats = 64 KiB

    dim3 grid(8, 8, 256);            // ceil(254/32)=8 tiles per dim, 256 batches
    pde_loss_main<<<grid, 256, 0, stream>>>(pred, rhs, Lk, Dk, RR, ZZ, partial);
    pde_loss_reduce<<<1, 256, 0, stream>>>(partial, 8 * 8 * 256, out);
}

// Round 4
// 238.383 us; speedup vs baseline: 1.2281x; 1.2281x over previous
//
#include <hip/hip_runtime.h>

#define HW 256
#define OW 254
#define RSTRIP 16            // output rows per wave strip
#define NBLOCK 1024          // 256 batches * 16 strips / 4 waves per block
#define NOUT (256.0f * 254.0f * 254.0f)

// Load 8 pred values: slots t=0..7 <-> columns c0-1+t of `row`.
// cL = max(c0-1,0)  (lane 0's slot0 is garbage -> only feeds masked GS col -1)
// cB = min(c0+4,HW-4) (lane 63's slots 5..7 garbage -> only feed masked cols)
__device__ __forceinline__ void load_row8(const float* __restrict__ base, int row,
                                          int cL, int c0, int cB, float* p) {
    p[0] = base[row * HW + cL];
    float4 v0 = *(const float4*)&base[row * HW + c0];
    p[1] = v0.x; p[2] = v0.y; p[3] = v0.z; p[4] = v0.w;
    float4 v1 = *(const float4*)&base[row * HW + cB];
    p[5] = v1.x; p[6] = v1.y; p[7] = v1.z;
}

__global__ __launch_bounds__(256) void pde_loss_main(
    const float* __restrict__ pred, const float* __restrict__ rhs,
    const float* __restrict__ Lk,   const float* __restrict__ Dk,
    const float* __restrict__ RR,   const float* __restrict__ ZZ,
    float* __restrict__ partial)
{
    const int tid  = threadIdx.x;
    const int lane = tid & 63;
    const int wv   = tid >> 6;
    const int gw   = blockIdx.x * 4 + wv;     // global wave id
    const int b    = gw >> 4;                 // 16 strips per batch
    const int strip= gw & 15;
    const int r0   = strip * RSTRIP;
    const int r1   = min(r0 + RSTRIP, OW);

    const float* predb = pred + (size_t)b * (HW * HW);
    const float* RRb   = RR   + (size_t)b * (HW * HW);
    const float* ZZb   = ZZ   + (size_t)b * (HW * HW);
    const float* rhsb  = rhs  + (size_t)b * (OW * OW);

    float kl[9], kd[9];
    #pragma unroll
    for (int q = 0; q < 9; q++) { kl[q] = Lk[b * 9 + q]; kd[q] = Dk[b * 9 + q]; }
    float hr = RRb[1 * HW + 2] - RRb[1 * HW + 1];
    float hz = ZZb[2 * HW + 1] - ZZb[1 * HW + 1];
    float hr2 = hr * hr, hz2 = hz * hz;
    const float scale = (-2.0f * (hr2 + hz2)) / (hr2 * hz2);

    const int c0 = lane * 4;             // output col base (0..252)
    const int cL = max(c0 - 1, 0);
    const int cB = min(c0 + 4, HW - 4);

    float pA[8], pB[8], pC[8];
    const int pa = max(r0 - 1, 0);
    load_row8(predb, pa,     cL, c0, cB, pA);   // pred row g   (for first g)
    load_row8(predb, pa + 1, cL, c0, cB, pB);   // pred row g+1

    float P[4] = {0, 0, 0, 0};   // = H[i-1] + 2*H[i] for upcoming output row i
    float Q[4] = {0, 0, 0, 0};   // = H[i]   (previous hb row)
    float acc = 0.0f;

    for (int g = r0 - 1; g <= r1; ++g) {
        float gs[6] = {0, 0, 0, 0, 0, 0};       // GS cols c0-1 .. c0+4 of row g
        if (g >= 0 && g < OW) {
            load_row8(predb, g + 2, cL, c0, cB, pC);
            float rq[6];                         // RR[g+1][c0 .. c0+5]
            float4 q0 = *(const float4*)&RRb[(g + 1) * HW + c0];
            rq[0] = q0.x; rq[1] = q0.y; rq[2] = q0.z; rq[3] = q0.w;
            float2 q1 = *(const float2*)&RRb[(g + 1) * HW + c0 + 4];
            rq[4] = q1.x; rq[5] = q1.y;

            #pragma unroll
            for (int u = 0; u < 6; ++u) {
                int x = c0 - 1 + u;              // conv-output col
                if (x >= 0 && x < OW) {
                    float sL = 0.0f, sD = 0.0f;
                    #pragma unroll
                    for (int kx = 0; kx < 3; ++kx) {
                        sL = fmaf(pA[u + kx], kl[kx],     sL);
                        sL = fmaf(pB[u + kx], kl[3 + kx], sL);
                        sL = fmaf(pC[u + kx], kl[6 + kx], sL);
                        sD = fmaf(pA[u + kx], kd[kx],     sD);
                        sD = fmaf(pB[u + kx], kd[3 + kx], sD);
                        sD = fmaf(pC[u + kx], kd[6 + kx], sD);
                    }
                    // GS = (Lpsi + convD/RR) * scale; rcp rel-err ~1e-7 << thr
                    gs[u] = scale * fmaf(sD, __builtin_amdgcn_rcpf(rq[u]), sL);
                }
            }
            #pragma unroll
            for (int t = 0; t < 8; ++t) { pA[t] = pB[t]; pB[t] = pC[t]; }
        }

        // horizontal (1,2,1): H[c0+t] from own gs[t..t+2] (no shuffles)
        float hb[4];
        #pragma unroll
        for (int t = 0; t < 4; ++t)
            hb[t] = gs[t] + 2.0f * gs[t + 1] + gs[t + 2];

        // output row i = g-1 completes: out = (H[i-1] + 2H[i] + H[i+1]) / 16
        const int i = g - 1;
        if (i >= r0) {                            // i < r1 holds by loop bound
            #pragma unroll
            for (int t = 0; t < 4; ++t) {
                int j = c0 + t;
                if (j < OW) {
                    float F = (P[t] + hb[t]) * (1.0f / 16.0f);
                    float d = F - rhsb[i * OW + j];
                    acc = fmaf(d, d, acc);
                }
            }
        }
        #pragma unroll
        for (int t = 0; t < 4; ++t) {
            P[t] = Q[t] + 2.0f * hb[t];
            Q[t] = hb[t];
        }
    }

    // wave (64) + block reduce (verbatim from passing R1/R2)
    #pragma unroll
    for (int off = 32; off > 0; off >>= 1)
        acc += __shfl_down(acc, off, 64);
    __shared__ float sw[4];
    if (lane == 0) sw[wv] = acc;
    __syncthreads();
    if (tid == 0)
        partial[blockIdx.x] = sw[0] + sw[1] + sw[2] + sw[3];
}

__global__ __launch_bounds__(256) void pde_loss_reduce(
    const float* __restrict__ partial, int n, float* __restrict__ out)
{
    float acc = 0.0f;
    for (int i = threadIdx.x; i < n; i += 256) acc += partial[i];
    #pragma unroll
    for (int off = 32; off > 0; off >>= 1)
        acc += __shfl_down(acc, off, 64);
    __shared__ float sw[4];
    if ((threadIdx.x & 63) == 0) sw[threadIdx.x >> 6] = acc;
    __syncthreads();
    if (threadIdx.x == 0)
        out[0] = (sw[0] + sw[1] + sw[2] + sw[3]) / NOUT;
}

extern "C" void kernel_launch(void* const* d_in, const int* in_sizes, int n_in,
                              void* d_out, int out_size, void* d_ws, size_t ws_size,
                              hipStream_t stream) {
    const float* pred = (const float*)d_in[0];
    const float* rhs  = (const float*)d_in[1];
    const float* Lk   = (const float*)d_in[2];
    const float* Dk   = (const float*)d_in[3];
    const float* RR   = (const float*)d_in[4];
    const float* ZZ   = (const float*)d_in[5];
    float* out = (float*)d_out;
    float* partial = (float*)d_ws;   // NBLOCK floats = 4 KiB

    pde_loss_main<<<NBLOCK, 256, 0, stream>>>(pred, rhs, Lk, Dk, RR, ZZ, partial);
    pde_loss_reduce<<<1, 256, 0, stream>>>(partial, NBLOCK, out);
}

// Round 5
// 236.133 us; speedup vs baseline: 1.2398x; 1.0095x over previous
//
#include <hip/hip_runtime.h>

#define HW 256
#define OW 254
#define RSTRIP 8             // output rows per wave strip
#define NBLOCK 2048          // 256 batches * 32 strips / 4 waves per block
#define NOUT (256.0f * 254.0f * 254.0f)

// Load 8 pred values: slots t=0..7 <-> columns c0-1+t of `row`.
// cL = max(c0-1,0): lane 0 slot0 garbage -> only feeds masked GS col -1.
// cB = min(c0+4,HW-4): lane 63 slots 5..7 garbage -> only feed masked cols.
__device__ __forceinline__ void load_row8(const float* __restrict__ base, int row,
                                          int cL, int c0, int cB, float* p) {
    p[0] = base[row * HW + cL];
    float4 v0 = *(const float4*)&base[row * HW + c0];
    p[1] = v0.x; p[2] = v0.y; p[3] = v0.z; p[4] = v0.w;
    float4 v1 = *(const float4*)&base[row * HW + cB];
    p[5] = v1.x; p[6] = v1.y; p[7] = v1.z;
}

// RR row slice cols c0..c0+5. row is pre-clamped to [1, HW-2] so flat index
// stays inside this batch's 64K plane even for lane 63 (cols 256,257 spill
// into row+1, which exists since row <= 254). Row>=1 avoids RR[0][0][0]==0
// ever reaching rcp (inf) on masked iterations.
__device__ __forceinline__ void load_rr6(const float* __restrict__ RRb, int row,
                                         int c0, float* rq) {
    float4 q0 = *(const float4*)&RRb[row * HW + c0];
    rq[0] = q0.x; rq[1] = q0.y; rq[2] = q0.z; rq[3] = q0.w;
    float2 q1 = *(const float2*)&RRb[row * HW + c0 + 4];
    rq[4] = q1.x; rq[5] = q1.y;
}

__device__ __forceinline__ void load_rhs4(const float* __restrict__ rhsb, int row,
                                          int c0, float* rh) {
    #pragma unroll
    for (int t = 0; t < 4; ++t)
        rh[t] = rhsb[row * OW + min(c0 + t, OW - 1)];  // clamp col: stay in-bounds
}

__device__ __forceinline__ float uniformf(float x) {
    return __int_as_float(__builtin_amdgcn_readfirstlane(__float_as_int(x)));
}

__global__ __launch_bounds__(256) void pde_loss_main(
    const float* __restrict__ pred, const float* __restrict__ rhs,
    const float* __restrict__ Lk,   const float* __restrict__ Dk,
    const float* __restrict__ RR,   const float* __restrict__ ZZ,
    float* __restrict__ partial)
{
    const int tid  = threadIdx.x;
    const int lane = tid & 63;
    const int wv   = tid >> 6;
    const int gw   = blockIdx.x * 4 + wv;     // global wave id
    const int b    = gw >> 5;                 // 32 strips per batch
    const int strip= gw & 31;
    const int r0   = strip * RSTRIP;
    const int r1   = min(r0 + RSTRIP, OW);

    const float* predb = pred + (size_t)b * (HW * HW);
    const float* RRb   = RR   + (size_t)b * (HW * HW);
    const float* ZZb   = ZZ   + (size_t)b * (HW * HW);
    const float* rhsb  = rhs  + (size_t)b * (OW * OW);

    // wave-uniform per-batch constants -> SGPRs (saves ~19 VGPRs)
    float kl[9], kd[9];
    #pragma unroll
    for (int q = 0; q < 9; q++) {
        kl[q] = uniformf(Lk[b * 9 + q]);
        kd[q] = uniformf(Dk[b * 9 + q]);
    }
    float hr = RRb[1 * HW + 2] - RRb[1 * HW + 1];
    float hz = ZZb[2 * HW + 1] - ZZb[1 * HW + 1];
    float hr2 = hr * hr, hz2 = hz * hz;
    const float scale = uniformf((-2.0f * (hr2 + hz2)) / (hr2 * hz2));

    const int c0 = lane * 4;             // output col base (0..252)
    const int cL = max(c0 - 1, 0);
    const int cB = min(c0 + 4, HW - 4);

    // pipeline state: at iteration g, pA/pB/pC = pred rows g,g+1,g+2 (clamped),
    // rq = RR row clamp(g+1,[1,254]), rh = rhs row clamp(g-1,[0,253]).
    float pA[8], pB[8], pC[8], pN[8];
    float rq[6], rqN[6], rh[4], rhN[4];

    load_row8(predb, max(r0 - 1, 0), cL, c0, cB, pA);
    load_row8(predb, r0,             cL, c0, cB, pB);
    load_row8(predb, r0 + 1,         cL, c0, cB, pC);
    load_rr6 (RRb,  min(max(r0, 1), HW - 2), c0, rq);
    load_rhs4(rhsb, max(r0 - 2, 0), c0, rh);

    float P[4] = {0, 0, 0, 0};   // = H[i-1] + 2*H[i] for upcoming output row i
    float Q[4] = {0, 0, 0, 0};   // = H[i]
    float acc = 0.0f;

    for (int g = r0 - 1; g <= r1; ++g) {
        // ---- prefetch everything iteration g+1 needs (branch-free, clamped) ----
        load_row8(predb, min(g + 3, HW - 1), cL, c0, cB, pN);
        load_rr6 (RRb,  min(max(g + 2, 1), HW - 2), c0, rqN);
        load_rhs4(rhsb, min(max(g, 0), OW - 1), c0, rhN);

        // ---- GS row g (cols c0-1 .. c0+4), masked outside [0,OW)^2 ----
        const bool rowok = (g >= 0) && (g < OW);
        float gs[6];
        #pragma unroll
        for (int u = 0; u < 6; ++u) {
            float sL = 0.0f, sD = 0.0f;
            #pragma unroll
            for (int kx = 0; kx < 3; ++kx) {
                sL = fmaf(pA[u + kx], kl[kx],     sL);
                sL = fmaf(pB[u + kx], kl[3 + kx], sL);
                sL = fmaf(pC[u + kx], kl[6 + kx], sL);
                sD = fmaf(pA[u + kx], kd[kx],     sD);
                sD = fmaf(pB[u + kx], kd[3 + kx], sD);
                sD = fmaf(pC[u + kx], kd[6 + kx], sD);
            }
            // GS = (Lpsi + convD/RR) * scale; rcp rel-err ~1e-7 << threshold.
            // rq is finite and nonzero by construction -> gval always finite.
            float gval = scale * fmaf(sD, __builtin_amdgcn_rcpf(rq[u]), sL);
            int x = c0 - 1 + u;
            gs[u] = (rowok && x >= 0 && x < OW) ? gval : 0.0f;
        }

        // horizontal (1,2,1)
        float hb[4];
        #pragma unroll
        for (int t = 0; t < 4; ++t)
            hb[t] = gs[t] + 2.0f * gs[t + 1] + gs[t + 2];

        // output row i = g-1 completes: out = (H[i-1] + 2H[i] + H[i+1]) / 16
        const int i = g - 1;
        const bool iok = (i >= r0);          // i < r1 holds by loop bound
        #pragma unroll
        for (int t = 0; t < 4; ++t) {
            float F = (P[t] + hb[t]) * (1.0f / 16.0f);
            float d = F - rh[t];
            acc += (iok && (c0 + t) < OW) ? d * d : 0.0f;
        }

        // ---- rotate pipeline ----
        #pragma unroll
        for (int t = 0; t < 8; ++t) { pA[t] = pB[t]; pB[t] = pC[t]; pC[t] = pN[t]; }
        #pragma unroll
        for (int u = 0; u < 6; ++u) rq[u] = rqN[u];
        #pragma unroll
        for (int t = 0; t < 4; ++t) {
            rh[t] = rhN[t];
            P[t] = Q[t] + 2.0f * hb[t];
            Q[t] = hb[t];
        }
    }

    // wave (64) + block reduce (verbatim from passing R1/R2/R4)
    #pragma unroll
    for (int off = 32; off > 0; off >>= 1)
        acc += __shfl_down(acc, off, 64);
    __shared__ float sw[4];
    if (lane == 0) sw[wv] = acc;
    __syncthreads();
    if (tid == 0)
        partial[blockIdx.x] = sw[0] + sw[1] + sw[2] + sw[3];
}

__global__ __launch_bounds__(256) void pde_loss_reduce(
    const float* __restrict__ partial, int n, float* __restrict__ out)
{
    float acc = 0.0f;
    for (int i = threadIdx.x; i < n; i += 256) acc += partial[i];
    #pragma unroll
    for (int off = 32; off > 0; off >>= 1)
        acc += __shfl_down(acc, off, 64);
    __shared__ float sw[4];
    if ((threadIdx.x & 63) == 0) sw[threadIdx.x >> 6] = acc;
    __syncthreads();
    if (threadIdx.x == 0)
        out[0] = (sw[0] + sw[1] + sw[2] + sw[3]) / NOUT;
}

extern "C" void kernel_launch(void* const* d_in, const int* in_sizes, int n_in,
                              void* d_out, int out_size, void* d_ws, size_t ws_size,
                              hipStream_t stream) {
    const float* pred = (const float*)d_in[0];
    const float* rhs  = (const float*)d_in[1];
    const float* Lk   = (const float*)d_in[2];
    const float* Dk   = (const float*)d_in[3];
    const float* RR   = (const float*)d_in[4];
    const float* ZZ   = (const float*)d_in[5];
    float* out = (float*)d_out;
    float* partial = (float*)d_ws;   // NBLOCK floats = 8 KiB

    pde_loss_main<<<NBLOCK, 256, 0, stream>>>(pred, rhs, Lk, Dk, RR, ZZ, partial);
    pde_loss_reduce<<<1, 256, 0, stream>>>(partial, NBLOCK, out);
}

// Round 6
// 234.595 us; speedup vs baseline: 1.2480x; 1.0066x over previous
//
#include <hip/hip_runtime.h>

#define HW 256
#define OW 254
#define RSTRIP 8             // output rows per wave strip
#define NITER (RSTRIP + 2)   // fixed trip count -> full unroll
#define NBLOCK 2048          // 256 batches * 32 strips / 4 waves per block
#define NOUT (256.0f * 254.0f * 254.0f)

// Load 8 pred values: slots t=0..7 <-> columns c0-1+t of `row`.
// cL = max(c0-1,0): lane 0 slot0 garbage -> only feeds masked GS col -1.
// cB = min(c0+4,HW-4): lane 63 slots 5..7 garbage -> only feed masked cols.
__device__ __forceinline__ void load_row8(const float* __restrict__ base, int row,
                                          int cL, int c0, int cB, float* p) {
    p[0] = base[row * HW + cL];
    float4 v0 = *(const float4*)&base[row * HW + c0];
    p[1] = v0.x; p[2] = v0.y; p[3] = v0.z; p[4] = v0.w;
    float4 v1 = *(const float4*)&base[row * HW + cB];
    p[5] = v1.x; p[6] = v1.y; p[7] = v1.z;
}

// RR row slice cols c0..c0+5. row pre-clamped to [1,HW-2] so even lane 63's
// spill (cols 256,257 -> next row) stays inside the batch plane, and
// RR[0][0][0]==0 never reaches rcp.
__device__ __forceinline__ void load_rr6(const float* __restrict__ RRb, int row,
                                         int c0, float* rq) {
    float4 q0 = *(const float4*)&RRb[row * HW + c0];
    rq[0] = q0.x; rq[1] = q0.y; rq[2] = q0.z; rq[3] = q0.w;
    float2 q1 = *(const float2*)&RRb[row * HW + c0 + 4];
    rq[4] = q1.x; rq[5] = q1.y;
}

// rhs cols c0..c0+3 as two float2 (8B aligned: row*254+c0 is even).
// c2 = min(c0+2, OW-4): lane 63 gets wrong-but-in-bounds data for slots 2,3,
// which only feed masked outputs (j >= OW).
__device__ __forceinline__ void load_rhs4v(const float* __restrict__ rhsb, int row,
                                           int c0, int c2, float* rh) {
    float2 a = *(const float2*)&rhsb[row * OW + c0];
    float2 b = *(const float2*)&rhsb[row * OW + c2];
    rh[0] = a.x; rh[1] = a.y; rh[2] = b.x; rh[3] = b.y;
}

__device__ __forceinline__ float uniformf(float x) {
    return __int_as_float(__builtin_amdgcn_readfirstlane(__float_as_int(x)));
}

__global__ __launch_bounds__(256) void pde_loss_main(
    const float* __restrict__ pred, const float* __restrict__ rhs,
    const float* __restrict__ Lk,   const float* __restrict__ Dk,
    const float* __restrict__ RR,   const float* __restrict__ ZZ,
    float* __restrict__ partial)
{
    const int tid  = threadIdx.x;
    const int lane = tid & 63;
    const int wv   = tid >> 6;
    const int gw   = blockIdx.x * 4 + wv;     // global wave id
    const int b    = gw >> 5;                 // 32 strips per batch
    const int strip= gw & 31;
    const int r0   = strip * RSTRIP;
    const int r1   = min(r0 + RSTRIP, OW);    // 254 for the last strip

    const float* predb = pred + (size_t)b * (HW * HW);
    const float* RRb   = RR   + (size_t)b * (HW * HW);
    const float* ZZb   = ZZ   + (size_t)b * (HW * HW);
    const float* rhsb  = rhs  + (size_t)b * (OW * OW);

    // wave-uniform per-batch constants -> SGPRs
    float kl[9], kd[9];
    #pragma unroll
    for (int q = 0; q < 9; q++) {
        kl[q] = uniformf(Lk[b * 9 + q]);
        kd[q] = uniformf(Dk[b * 9 + q]);
    }
    float hr = RRb[1 * HW + 2] - RRb[1 * HW + 1];
    float hz = ZZb[2 * HW + 1] - ZZb[1 * HW + 1];
    float hr2 = hr * hr, hz2 = hz * hz;
    const float scale = uniformf((-2.0f * (hr2 + hz2)) / (hr2 * hz2));

    const int c0 = lane * 4;             // output col base (0..252)
    const int cL = max(c0 - 1, 0);
    const int cB = min(c0 + 4, HW - 4);
    const int c2 = min(c0 + 2, OW - 4);

    // GS row g uses pred rows g,g+1,g+2 = pA,pB,pC
    float pA[8], pB[8];
    load_row8(predb, max(r0 - 1, 0), cL, c0, cB, pA);   // row g=r0-1 (clamped)
    load_row8(predb, r0,             cL, c0, cB, pB);   // row r0

    float P[4] = {0, 0, 0, 0};   // = H[i-1] + 2*H[i] for upcoming output row i
    float Q[4] = {0, 0, 0, 0};   // = H[i]
    float acc = 0.0f;

    #pragma unroll
    for (int s = 0; s < NITER; ++s) {
        const int g = r0 - 1 + s;            // GS row of this iteration

        float pC[8], rq[6], rh[4];
        load_row8(predb, min(g + 2, HW - 1), cL, c0, cB, pC);
        load_rr6 (RRb,  min(max(g + 1, 1), HW - 2), c0, rq);
        load_rhs4v(rhsb, min(max(g - 1, 0), OW - 1), c0, c2, rh);

        // ---- GS row g (cols c0-1 .. c0+4), masked outside [0,OW)^2 ----
        const bool rowok = (g >= 0) && (g < OW);
        float gs[6];
        #pragma unroll
        for (int u = 0; u < 6; ++u) {
            float sL = 0.0f, sD = 0.0f;
            #pragma unroll
            for (int kx = 0; kx < 3; ++kx) {
                sL = fmaf(pA[u + kx], kl[kx],     sL);
                sL = fmaf(pB[u + kx], kl[3 + kx], sL);
                sL = fmaf(pC[u + kx], kl[6 + kx], sL);
                sD = fmaf(pA[u + kx], kd[kx],     sD);
                sD = fmaf(pB[u + kx], kd[3 + kx], sD);
                sD = fmaf(pC[u + kx], kd[6 + kx], sD);
            }
            // GS = (Lpsi + convD/RR) * scale; rcp rel-err ~1e-7 << threshold.
            float gval = scale * fmaf(sD, __builtin_amdgcn_rcpf(rq[u]), sL);
            int x = c0 - 1 + u;
            gs[u] = (rowok && x >= 0 && x < OW) ? gval : 0.0f;
        }

        // horizontal (1,2,1)
        float hb[4];
        #pragma unroll
        for (int t = 0; t < 4; ++t)
            hb[t] = gs[t] + 2.0f * gs[t + 1] + gs[t + 2];

        // output row i = g-1: out = (H[i-1] + 2H[i] + H[i+1]) / 16
        const int i = g - 1;
        const bool iok = (s >= 2) && (i < r1);   // i>=r0 iff s>=2; i<r1 trims last strip
        #pragma unroll
        for (int t = 0; t < 4; ++t) {
            float F = (P[t] + hb[t]) * (1.0f / 16.0f);
            float d = F - rh[t];
            acc += (iok && (c0 + t) < OW) ? d * d : 0.0f;
        }

        // roll accumulators + pred ring (pure SSA after full unroll)
        #pragma unroll
        for (int t = 0; t < 4; ++t) {
            P[t] = Q[t] + 2.0f * hb[t];
            Q[t] = hb[t];
        }
        #pragma unroll
        for (int t = 0; t < 8; ++t) { pA[t] = pB[t]; pB[t] = pC[t]; }
    }

    // wave (64) + block reduce (verbatim from passing R1/R2/R4/R5)
    #pragma unroll
    for (int off = 32; off > 0; off >>= 1)
        acc += __shfl_down(acc, off, 64);
    __shared__ float sw[4];
    if (lane == 0) sw[wv] = acc;
    __syncthreads();
    if (tid == 0)
        partial[blockIdx.x] = sw[0] + sw[1] + sw[2] + sw[3];
}

__global__ __launch_bounds__(256) void pde_loss_reduce(
    const float* __restrict__ partial, int n, float* __restrict__ out)
{
    float acc = 0.0f;
    for (int i = threadIdx.x; i < n; i += 256) acc += partial[i];
    #pragma unroll
    for (int off = 32; off > 0; off >>= 1)
        acc += __shfl_down(acc, off, 64);
    __shared__ float sw[4];
    if ((threadIdx.x & 63) == 0) sw[threadIdx.x >> 6] = acc;
    __syncthreads();
    if (threadIdx.x == 0)
        out[0] = (sw[0] + sw[1] + sw[2] + sw[3]) / NOUT;
}

extern "C" void kernel_launch(void* const* d_in, const int* in_sizes, int n_in,
                              void* d_out, int out_size, void* d_ws, size_t ws_size,
                              hipStream_t stream) {
    const float* pred = (const float*)d_in[0];
    const float* rhs  = (const float*)d_in[1];
    const float* Lk   = (const float*)d_in[2];
    const float* Dk   = (const float*)d_in[3];
    const float* RR   = (const float*)d_in[4];
    const float* ZZ   = (const float*)d_in[5];
    float* out = (float*)d_out;
    float* partial = (float*)d_ws;   // NBLOCK floats = 8 KiB

    pde_loss_main<<<NBLOCK, 256, 0, stream>>>(pred, rhs, Lk, Dk, RR, ZZ, partial);
    pde_loss_reduce<<<1, 256, 0, stream>>>(partial, NBLOCK, out);
}

// Round 7
// 225.957 us; speedup vs baseline: 1.2957x; 1.0382x over previous
//
#include <hip/hip_runtime.h>

#define HW 256
#define OW 254
#define RSTRIP 6             // output rows per wave strip
#define NSTRIPS 43           // ceil(254/6); strip 42 covers rows 252..253
#define NWAVES (256 * NSTRIPS)
#define NBLOCK (NWAVES / 4)  // 2752
#define NGS (RSTRIP + 2)     // gs rows per strip
#define NOUT (256.0f * 254.0f * 254.0f)

// Load 8 pred values: slots t=0..7 <-> columns c0-1+t of `row`.
// cL = max(c0-1,0): lane 0 slot0 garbage -> only feeds masked GS col -1.
// cB = min(c0+4,HW-4): lane 63 slots 5..7 garbage -> only feed masked cols.
__device__ __forceinline__ void load_row8(const float* __restrict__ base, int row,
                                          int cL, int c0, int cB, float* p) {
    p[0] = base[row * HW + cL];
    float4 v0 = *(const float4*)&base[row * HW + c0];
    p[1] = v0.x; p[2] = v0.y; p[3] = v0.z; p[4] = v0.w;
    float4 v1 = *(const float4*)&base[row * HW + cB];
    p[5] = v1.x; p[6] = v1.y; p[7] = v1.z;
}

// RR row slice cols c0..c0+5; row pre-clamped to [1,HW-2] (lane 63 spill stays
// in-plane; RR[0][0][0]==0 never reaches rcp).
__device__ __forceinline__ void load_rr6(const float* __restrict__ RRb, int row,
                                         int c0, float* rq) {
    float4 q0 = *(const float4*)&RRb[row * HW + c0];
    rq[0] = q0.x; rq[1] = q0.y; rq[2] = q0.z; rq[3] = q0.w;
    float2 q1 = *(const float2*)&RRb[row * HW + c0 + 4];
    rq[4] = q1.x; rq[5] = q1.y;
}

// rhs cols c0..c0+3 as two float2 (8B-aligned: row*254+c0 even).
// c2 = min(c0+2, OW-4): lane 63 slots 2,3 wrong-but-in-bounds, masked later.
__device__ __forceinline__ void load_rhs4v(const float* __restrict__ rhsb, int row,
                                           int c0, int c2, float* rh) {
    float2 a = *(const float2*)&rhsb[row * OW + c0];
    float2 b = *(const float2*)&rhsb[row * OW + c2];
    rh[0] = a.x; rh[1] = a.y; rh[2] = b.x; rh[3] = b.y;
}

__device__ __forceinline__ float uniformf(float x) {
    return __int_as_float(__builtin_amdgcn_readfirstlane(__float_as_int(x)));
}

__global__ __launch_bounds__(256, 1) void pde_loss_main(
    const float* __restrict__ pred, const float* __restrict__ rhs,
    const float* __restrict__ Lk,   const float* __restrict__ Dk,
    const float* __restrict__ RR,   const float* __restrict__ ZZ,
    float* __restrict__ partial)
{
    const int tid  = threadIdx.x;
    const int lane = tid & 63;
    const int wv   = tid >> 6;
    const int gw   = blockIdx.x * 4 + wv;     // global wave id (< NWAVES)
    const int b    = gw / NSTRIPS;            // magic-mul division
    const int strip= gw - b * NSTRIPS;
    const int r0   = strip * RSTRIP;
    const int r1   = min(r0 + RSTRIP, OW);

    const float* predb = pred + (size_t)b * (HW * HW);
    const float* RRb   = RR   + (size_t)b * (HW * HW);
    const float* ZZb   = ZZ   + (size_t)b * (HW * HW);
    const float* rhsb  = rhs  + (size_t)b * (OW * OW);

    // wave-uniform per-batch constants -> SGPRs
    float kl[9], kd[9];
    #pragma unroll
    for (int q = 0; q < 9; q++) {
        kl[q] = uniformf(Lk[b * 9 + q]);
        kd[q] = uniformf(Dk[b * 9 + q]);
    }
    float hr = RRb[1 * HW + 2] - RRb[1 * HW + 1];
    float hz = ZZb[2 * HW + 1] - ZZb[1 * HW + 1];
    float hr2 = hr * hr, hz2 = hz * hz;
    const float scale = uniformf((-2.0f * (hr2 + hz2)) / (hr2 * hz2));

    const int c0 = lane * 4;             // output col base (0..252)
    const int cL = max(c0 - 1, 0);
    const int cB = min(c0 + 4, HW - 4);
    const int c2 = min(c0 + 2, OW - 4);

    // ======== LOAD PHASE: entire strip into registers (max MLP) ========
    // pred rows r0-1 .. r0+8 (for gs rows g=r0-1..r0+6 needing g..g+2)
    float p[NGS + 2][8];
    #pragma unroll
    for (int s = 0; s < NGS + 2; ++s)
        load_row8(predb, min(max(r0 - 1 + s, 0), HW - 1), cL, c0, cB, p[s]);
    // RR rows g+1 = r0+s, s=0..7, clamped to [1,254]
    float rq[NGS][6];
    #pragma unroll
    for (int s = 0; s < NGS; ++s)
        load_rr6(RRb, min(max(r0 + s, 1), HW - 2), c0, rq[s]);
    // rhs rows i = r0..r0+5 (clamped; overflow rows masked in compute)
    float rh[RSTRIP][4];
    #pragma unroll
    for (int s = 0; s < RSTRIP; ++s)
        load_rhs4v(rhsb, min(r0 + s, OW - 1), c0, c2, rh[s]);

    // fence: do NOT let the scheduler sink these loads into the compute
    __builtin_amdgcn_sched_barrier(0);

    // ======== COMPUTE PHASE: pure VALU, fully unrolled ========
    float P[4] = {0, 0, 0, 0};   // = H[i-1] + 2*H[i] for upcoming output row i
    float Q[4] = {0, 0, 0, 0};   // = H[i]
    float acc = 0.0f;

    #pragma unroll
    for (int s = 0; s < NGS; ++s) {
        const int g = r0 - 1 + s;            // GS row
        const bool rowok = (g >= 0) && (g < OW);

        float gs[6];
        #pragma unroll
        for (int u = 0; u < 6; ++u) {
            float sL = 0.0f, sD = 0.0f;
            #pragma unroll
            for (int kx = 0; kx < 3; ++kx) {
                sL = fmaf(p[s][u + kx],     kl[kx],     sL);
                sL = fmaf(p[s + 1][u + kx], kl[3 + kx], sL);
                sL = fmaf(p[s + 2][u + kx], kl[6 + kx], sL);
                sD = fmaf(p[s][u + kx],     kd[kx],     sD);
                sD = fmaf(p[s + 1][u + kx], kd[3 + kx], sD);
                sD = fmaf(p[s + 2][u + kx], kd[6 + kx], sD);
            }
            // GS = (Lpsi + convD/RR) * scale; rcp rel-err ~1e-7 << threshold
            float gval = scale * fmaf(sD, __builtin_amdgcn_rcpf(rq[s][u]), sL);
            int x = c0 - 1 + u;
            gs[u] = (rowok && x >= 0 && x < OW) ? gval : 0.0f;
        }

        // horizontal (1,2,1)
        float hb[4];
        #pragma unroll
        for (int t = 0; t < 4; ++t)
            hb[t] = gs[t] + 2.0f * gs[t + 1] + gs[t + 2];

        // output row i = g-1 completes: out = (H[i-1] + 2H[i] + H[i+1]) / 16
        const int i = g - 1;
        const bool iok = (s >= 2) && (i < r1);
        const float* rhrow = rh[(s >= 2) ? (s - 2) : 0];
        #pragma unroll
        for (int t = 0; t < 4; ++t) {
            float F = (P[t] + hb[t]) * (1.0f / 16.0f);
            float d = F - rhrow[t];
            acc += (iok && (c0 + t) < OW) ? d * d : 0.0f;
        }

        #pragma unroll
        for (int t = 0; t < 4; ++t) {
            P[t] = Q[t] + 2.0f * hb[t];
            Q[t] = hb[t];
        }
    }

    // wave (64) + block reduce (verbatim from passing R4/R5/R6)
    #pragma unroll
    for (int off = 32; off > 0; off >>= 1)
        acc += __shfl_down(acc, off, 64);
    __shared__ float sw[4];
    if (lane == 0) sw[wv] = acc;
    __syncthreads();
    if (tid == 0)
        partial[blockIdx.x] = sw[0] + sw[1] + sw[2] + sw[3];
}

__global__ __launch_bounds__(256) void pde_loss_reduce(
    const float* __restrict__ partial, int n, float* __restrict__ out)
{
    float acc = 0.0f;
    for (int i = threadIdx.x; i < n; i += 256) acc += partial[i];
    #pragma unroll
    for (int off = 32; off > 0; off >>= 1)
        acc += __shfl_down(acc, off, 64);
    __shared__ float sw[4];
    if ((threadIdx.x & 63) == 0) sw[threadIdx.x >> 6] = acc;
    __syncthreads();
    if (threadIdx.x == 0)
        out[0] = (sw[0] + sw[1] + sw[2] + sw[3]) / NOUT;
}

extern "C" void kernel_launch(void* const* d_in, const int* in_sizes, int n_in,
                              void* d_out, int out_size, void* d_ws, size_t ws_size,
                              hipStream_t stream) {
    const float* pred = (const float*)d_in[0];
    const float* rhs  = (const float*)d_in[1];
    const float* Lk   = (const float*)d_in[2];
    const float* Dk   = (const float*)d_in[3];
    const float* RR   = (const float*)d_in[4];
    const float* ZZ   = (const float*)d_in[5];
    float* out = (float*)d_out;
    float* partial = (float*)d_ws;   // NBLOCK floats = 11 KiB

    pde_loss_main<<<NBLOCK, 256, 0, stream>>>(pred, rhs, Lk, Dk, RR, ZZ, partial);
    pde_loss_reduce<<<1, 256, 0, stream>>>(partial, NBLOCK, out);
}